// Round 8
// baseline (592.307 us; speedup 1.0000x reference)
//
#include <hip/hip_runtime.h>
#include <hip/hip_bf16.h>
#include <cstdint>

static constexpr int NS_N = 50000;
static constexpr int ND_N = 50000;
static constexpr int E_N  = 500000;

__device__ __forceinline__ float sigm(float x) { return 1.f / (1.f + __expf(-x)); }

__device__ __forceinline__ unsigned short f2bf(float f) {
  __hip_bfloat16 h = __float2bfloat16(f);   // RTNE
  return *reinterpret_cast<unsigned short*>(&h);
}

// ---------------- one-time weight transpose into workspace: Wt[k][j] = W[j][k] ----------------
// wt layout (floats): proj 4x16384 @0 | W1 2x8192 @65536 | W2 2x4096 @81920 |
//                     scW 6144 @90112 | devW 4096 @96256  (total 100352)
__global__ void transpose_w_kernel(const float* __restrict__ projW,
                                   const float* __restrict__ W1,
                                   const float* __restrict__ W2,
                                   const float* __restrict__ scW,
                                   const float* __restrict__ devW,
                                   float* __restrict__ wt) {
  const int id = blockIdx.y;
  const float* src; float* dst; int Mm, Kk;
  if (id < 4)      { src = projW + id * 16384;       dst = wt + id * 16384;            Mm = 128; Kk = 128; }
  else if (id < 6) { src = W1 + (id - 4) * 8192;     dst = wt + 65536 + (id - 4) * 8192; Mm = 64; Kk = 128; }
  else if (id < 8) { src = W2 + (id - 6) * 4096;     dst = wt + 81920 + (id - 6) * 4096; Mm = 64; Kk = 64; }
  else if (id == 8){ src = scW;                      dst = wt + 90112;                 Mm = 128; Kk = 48; }
  else             { src = devW;                     dst = wt + 96256;                 Mm = 128; Kk = 32; }
  const int total = Mm * Kk;
  for (int i = blockIdx.x * 256 + threadIdx.x; i < total; i += gridDim.x * 256) {
    int j = i / Kk, k = i % Kk;
    dst[k * Mm + j] = src[i];
  }
}

// ---------------- CSR build (scan-free) ----------------
__global__ void count2_kernel(const int* __restrict__ dsd, const int* __restrict__ dds,
                              int* __restrict__ cnt, int n) {
  int i = blockIdx.x * blockDim.x + threadIdx.x;
  if (i < n) {
    atomicAdd(&cnt[dsd[i]], 1);
    atomicAdd(&cnt[ND_N + dds[i]], 1);
  }
}

__global__ void alloc_kernel(const int* __restrict__ cnt, int* __restrict__ rp,
                             int* __restrict__ cur, int* __restrict__ totals, int n) {
  const int y = blockIdx.y;
  const int* c = cnt + (size_t)y * n;
  int* r = rp + (size_t)y * n;
  int* q = cur + (size_t)y * n;
  const int i = blockIdx.x * 256 + threadIdx.x;
  const int lane = threadIdx.x & 63;
  int v = (i < n) ? c[i] : 0;
  int incl = v;
  #pragma unroll
  for (int off = 1; off < 64; off <<= 1) {
    int t = __shfl_up(incl, off);
    if (lane >= off) incl += t;
  }
  int tot = __shfl(incl, 63);
  int base = 0;
  if (lane == 0) base = atomicAdd(&totals[y], tot);
  base = __shfl(base, 0);
  if (i < n) {
    int st = base + incl - v;
    r[i] = st;
    q[i] = st;
  }
}

__global__ void fill2_kernel(const int* __restrict__ e_sd, const int* __restrict__ e_ds,
                             int* __restrict__ cur,
                             int* __restrict__ csr_sd, int* __restrict__ csr_ds, int n) {
  const int y = blockIdx.y;
  const int* e = y ? e_ds : e_sd;
  int* csr = y ? csr_ds : csr_sd;
  int* q = cur + (size_t)y * 50000;
  int i = blockIdx.x * blockDim.x + threadIdx.x;
  if (i < n) {
    int d = e[E_N + i];
    int pos = atomicAdd(&q[d], 1);
    csr[pos] = e[i];
  }
}

// ---------------- dense7: no-LDS register-tiled f32 GEMM, W^T direct from global ----------------
// Wt is pre-transposed [K][M]. Lane colq reads float4 Wt[k*M+4colq]: 512B contiguous/wave,
// L1/L2 broadcast across blocks. x rows are wave-broadcast reads. No barriers, no conflicts.
template<int K, int M, int BN, bool RELU, bool SCORES, bool DUAL>
__global__ __launch_bounds__(256) void dense7_kernel(
    const float* __restrict__ in0, const float* __restrict__ Wt0,
    const float* __restrict__ b0, void* __restrict__ out0,
    const float* __restrict__ aA0, const float* __restrict__ aB0,
    float* __restrict__ oA0, float* __restrict__ oB0,
    const float* __restrict__ in1, const float* __restrict__ Wt1,
    const float* __restrict__ b1x, void* __restrict__ out1,
    const float* __restrict__ aA1, const float* __restrict__ aB1,
    float* __restrict__ oA1, float* __restrict__ oB1, int N)
{
  static_assert(M % 4 == 0 && K % 4 == 0, "");
  constexpr int COLG = M / 4;
  constexpr int NODEG = 256 / COLG;
  constexpr int TM = BN / NODEG;
  static_assert(BN % NODEG == 0 && 256 % COLG == 0, "");
  const float* in_ = in0; const float* Wt = Wt0; const float* b = b0; void* out_ = out0;
  const float* aA = aA0; const float* aB = aB0; float* oA = oA0; float* oB = oB0;
  if constexpr (DUAL) {
    if (blockIdx.y) {
      in_ = in1; Wt = Wt1; b = b1x; out_ = out1;
      aA = aA1; aB = aB1; oA = oA1; oB = oB1;
    }
  }
  const int tid = threadIdx.x;
  const int colq = tid % COLG;
  const int nodeg = tid / COLG;
  const int nb = blockIdx.x * BN;
  const float* xbase[TM];
  #pragma unroll
  for (int t = 0; t < TM; ++t) {
    int n = nb + nodeg * TM + t;
    xbase[t] = in_ + (size_t)(n < N ? n : N - 1) * K;  // clamp: discard at store
  }
  const float4 bv = *(const float4*)&b[4 * colq];
  float acc[TM][4];
  #pragma unroll
  for (int t = 0; t < TM; ++t) {
    acc[t][0] = bv.x; acc[t][1] = bv.y; acc[t][2] = bv.z; acc[t][3] = bv.w;
  }
  #pragma unroll 2
  for (int k = 0; k < K; k += 4) {
    const float4 wv0 = *(const float4*)&Wt[(size_t)(k + 0) * M + 4 * colq];
    const float4 wv1 = *(const float4*)&Wt[(size_t)(k + 1) * M + 4 * colq];
    const float4 wv2 = *(const float4*)&Wt[(size_t)(k + 2) * M + 4 * colq];
    const float4 wv3 = *(const float4*)&Wt[(size_t)(k + 3) * M + 4 * colq];
    #pragma unroll
    for (int t = 0; t < TM; ++t) {
      const float4 xv = *(const float4*)(xbase[t] + k);
      acc[t][0] += xv.x * wv0.x + xv.y * wv1.x + xv.z * wv2.x + xv.w * wv3.x;
      acc[t][1] += xv.x * wv0.y + xv.y * wv1.y + xv.z * wv2.y + xv.w * wv3.y;
      acc[t][2] += xv.x * wv0.z + xv.y * wv1.z + xv.z * wv2.z + xv.w * wv3.z;
      acc[t][3] += xv.x * wv0.w + xv.y * wv1.w + xv.z * wv2.w + xv.w * wv3.w;
    }
  }
  if constexpr (!SCORES) {
    float* op = (float*)out_;
    #pragma unroll
    for (int t = 0; t < TM; ++t) {
      int n = nb + nodeg * TM + t;
      if (n < N) {
        float4 v = make_float4(acc[t][0], acc[t][1], acc[t][2], acc[t][3]);
        if constexpr (RELU) {
          v.x = fmaxf(v.x, 0.f); v.y = fmaxf(v.y, 0.f);
          v.z = fmaxf(v.z, 0.f); v.w = fmaxf(v.w, 0.f);
        }
        *(float4*)&op[(size_t)n * M + 4 * colq] = v;
      }
    }
  } else {
    unsigned short* op = (unsigned short*)out_;
    const float4 vA = *(const float4*)&aA[4 * colq];
    const float4 vB = *(const float4*)&aB[4 * colq];
    #pragma unroll
    for (int t = 0; t < TM; ++t) {
      int n = nb + nodeg * TM + t;
      if (n < N) {
        ushort4 u;
        u.x = f2bf(acc[t][0]); u.y = f2bf(acc[t][1]);
        u.z = f2bf(acc[t][2]); u.w = f2bf(acc[t][3]);
        *(ushort4*)&op[(size_t)n * M + 4 * colq] = u;
      }
      float pa = acc[t][0] * vA.x + acc[t][1] * vA.y + acc[t][2] * vA.z + acc[t][3] * vA.w;
      float pb = acc[t][0] * vB.x + acc[t][1] * vB.y + acc[t][2] * vB.z + acc[t][3] * vB.w;
      pa += __shfl_xor(pa, 1); pa += __shfl_xor(pa, 2);
      pb += __shfl_xor(pb, 1); pb += __shfl_xor(pb, 2);
      if ((colq & 3) == 0 && n < N) {
        oA[(size_t)n * 8 + (colq >> 2)] = pa;
        oB[(size_t)n * 8 + (colq >> 2)] = pb;
      }
    }
  }
}

// ---------------- fused encoders v2: y=0 stream LSTM+dense48, y=1 device dense32; W^T global ----------------
__global__ __launch_bounds__(256) void enc_fused2_kernel(
    const float* __restrict__ xs,
    const float* __restrict__ W_ih, const float* __restrict__ b_ih,
    const float* __restrict__ b_hh,
    const float* __restrict__ scWt, const float* __restrict__ scb,
    float* __restrict__ h0out,
    const float* __restrict__ xd,
    const float* __restrict__ devWt, const float* __restrict__ devb,
    float* __restrict__ h1out, int N)
{
  constexpr int M = 128, BN = 64, COLG = 32, TM = 8;
  __shared__ float xl[BN * 48];
  const int tid = threadIdx.x;
  const int colq = tid % COLG;
  const int nodeg = tid / COLG;
  const int nb = blockIdx.x * BN;

  if (blockIdx.y == 0) {
    constexpr int K = 48;
    for (int idx = tid; idx < BN * 16; idx += 256) {
      int n = idx >> 4, f = idx & 15;
      xl[n * K + f] = (nb + n < N) ? xs[(size_t)(nb + n) * 17 + f] : 0.f;
    }
    for (int idx = tid; idx < BN * 32; idx += 256) {
      int n = idx >> 5, jj = idx & 31;
      float h = 0.f;
      if (nb + n < N) {
        float xr = xs[(size_t)(nb + n) * 17 + 16];
        float gi = xr * W_ih[jj]      + b_ih[jj]      + b_hh[jj];
        float gg = xr * W_ih[64 + jj] + b_ih[64 + jj] + b_hh[64 + jj];
        float go = xr * W_ih[96 + jj] + b_ih[96 + jj] + b_hh[96 + jj];
        float c = sigm(gi) * tanhf(gg);
        h = sigm(go) * tanhf(c);
      }
      xl[n * K + 16 + jj] = h;
    }
    __syncthreads();
    const float4 bv = *(const float4*)&scb[4 * colq];
    float acc[TM][4];
    #pragma unroll
    for (int t = 0; t < TM; ++t) {
      acc[t][0] = bv.x; acc[t][1] = bv.y; acc[t][2] = bv.z; acc[t][3] = bv.w;
    }
    #pragma unroll 2
    for (int k = 0; k < K; k += 4) {
      const float4 wv0 = *(const float4*)&scWt[(size_t)(k + 0) * M + 4 * colq];
      const float4 wv1 = *(const float4*)&scWt[(size_t)(k + 1) * M + 4 * colq];
      const float4 wv2 = *(const float4*)&scWt[(size_t)(k + 2) * M + 4 * colq];
      const float4 wv3 = *(const float4*)&scWt[(size_t)(k + 3) * M + 4 * colq];
      #pragma unroll
      for (int t = 0; t < TM; ++t) {
        const float4 xv = *(const float4*)&xl[(nodeg * TM + t) * K + k];
        acc[t][0] += xv.x * wv0.x + xv.y * wv1.x + xv.z * wv2.x + xv.w * wv3.x;
        acc[t][1] += xv.x * wv0.y + xv.y * wv1.y + xv.z * wv2.y + xv.w * wv3.y;
        acc[t][2] += xv.x * wv0.z + xv.y * wv1.z + xv.z * wv2.z + xv.w * wv3.z;
        acc[t][3] += xv.x * wv0.w + xv.y * wv1.w + xv.z * wv2.w + xv.w * wv3.w;
      }
    }
    #pragma unroll
    for (int t = 0; t < TM; ++t) {
      int n = nb + nodeg * TM + t;
      if (n < N) {
        *(float4*)&h0out[(size_t)n * M + 4 * colq] =
            make_float4(fmaxf(acc[t][0], 0.f), fmaxf(acc[t][1], 0.f),
                        fmaxf(acc[t][2], 0.f), fmaxf(acc[t][3], 0.f));
      }
    }
  } else {
    constexpr int K = 32;
    const float* xbase[TM];
    #pragma unroll
    for (int t = 0; t < TM; ++t) {
      int n = nb + nodeg * TM + t;
      xbase[t] = xd + (size_t)(n < N ? n : N - 1) * K;
    }
    const float4 bv = *(const float4*)&devb[4 * colq];
    float acc[TM][4];
    #pragma unroll
    for (int t = 0; t < TM; ++t) {
      acc[t][0] = bv.x; acc[t][1] = bv.y; acc[t][2] = bv.z; acc[t][3] = bv.w;
    }
    #pragma unroll 2
    for (int k = 0; k < K; k += 4) {
      const float4 wv0 = *(const float4*)&devWt[(size_t)(k + 0) * M + 4 * colq];
      const float4 wv1 = *(const float4*)&devWt[(size_t)(k + 1) * M + 4 * colq];
      const float4 wv2 = *(const float4*)&devWt[(size_t)(k + 2) * M + 4 * colq];
      const float4 wv3 = *(const float4*)&devWt[(size_t)(k + 3) * M + 4 * colq];
      #pragma unroll
      for (int t = 0; t < TM; ++t) {
        const float4 xv = *(const float4*)(xbase[t] + k);
        acc[t][0] += xv.x * wv0.x + xv.y * wv1.x + xv.z * wv2.x + xv.w * wv3.x;
        acc[t][1] += xv.x * wv0.y + xv.y * wv1.y + xv.z * wv2.y + xv.w * wv3.y;
        acc[t][2] += xv.x * wv0.z + xv.y * wv1.z + xv.z * wv2.z + xv.w * wv3.z;
        acc[t][3] += xv.x * wv0.w + xv.y * wv1.w + xv.z * wv2.w + xv.w * wv3.w;
      }
    }
    #pragma unroll
    for (int t = 0; t < TM; ++t) {
      int n = nb + nodeg * TM + t;
      if (n < N) {
        *(float4*)&h1out[(size_t)n * M + 4 * colq] =
            make_float4(fmaxf(acc[t][0], 0.f), fmaxf(acc[t][1], 0.f),
                        fmaxf(acc[t][2], 0.f), fmaxf(acc[t][3], 0.f));
      }
    }
  }
}

// ---------------- att_agg5: head-x-edge lane layout for scores, bf16 gather ----------------
#define CAP 128
__global__ __launch_bounds__(256) void att_agg5_kernel(
    const int* __restrict__ rp0, const int* __restrict__ dg0, const int* __restrict__ csr0,
    const float* __restrict__ asrc0, const float* __restrict__ adst0,
    const unsigned short* __restrict__ x0, float* __restrict__ o0,
    const int* __restrict__ rp1, const int* __restrict__ dg1, const int* __restrict__ csr1,
    const float* __restrict__ asrc1, const float* __restrict__ adst1,
    const unsigned short* __restrict__ x1, float* __restrict__ o1, int n_dst)
{
  const int y = blockIdx.y;
  const int* rp      = y ? rp1 : rp0;
  const int* dgs     = y ? dg1 : dg0;
  const int* csr     = y ? csr1 : csr0;
  const float* a_src = y ? asrc1 : asrc0;
  const float* a_dst = y ? adst1 : adst0;
  const uint32_t* xr = (const uint32_t*)(y ? x1 : x0);
  float* out         = y ? o1 : o0;

  __shared__ float wexp[4][8][CAP + 4];
  __shared__ int   sidx[4][CAP];
  const int lane = threadIdx.x & 63;
  const int w = threadIdx.x >> 6;
  const int h = lane >> 3;
  const int e = lane & 7;
  const int dst = blockIdx.x * 4 + w;
  if (dst >= n_dst) return;
  const int start = rp[dst];
  const int deg = dgs[dst];
  const int dcap = deg < CAP ? deg : CAP;
  const float adh = a_dst[(size_t)dst * 8 + h];

  float m = -3.0e38f;
  for (int jj = e; jj < deg; jj += 8) {
    int s = csr[start + jj];
    float v = a_src[(size_t)s * 8 + h] + adh;
    v = (v >= 0.f) ? v : 0.2f * v;
    if (jj < CAP) {
      wexp[w][h][jj] = v;
      if (h == 0) sidx[w][jj] = s;
    }
    m = fmaxf(m, v);
  }
  m = fmaxf(m, __shfl_xor(m, 1));
  m = fmaxf(m, __shfl_xor(m, 2));
  m = fmaxf(m, __shfl_xor(m, 4));

  float ssum = 0.f;
  for (int jj = e; jj < dcap; jj += 8) {
    float ev = __expf(wexp[w][h][jj] - m);
    wexp[w][h][jj] = ev;
    ssum += ev;
  }
  for (int jj = CAP + e; jj < deg; jj += 8) {
    int s = csr[start + jj];
    float v = a_src[(size_t)s * 8 + h] + adh;
    v = (v >= 0.f) ? v : 0.2f * v;
    ssum += __expf(v - m);
  }
  ssum += __shfl_xor(ssum, 1);
  ssum += __shfl_xor(ssum, 2);
  ssum += __shfl_xor(ssum, 4);
  const float invh = 1.f / (ssum + 1e-16f);

  float ax0 = 0.f, ay0 = 0.f, ax1 = 0.f, ay1 = 0.f;
  int jj = 0;
  for (; jj + 4 <= dcap; jj += 4) {
    int s0 = sidx[w][jj], s1 = sidx[w][jj+1], s2 = sidx[w][jj+2], s3 = sidx[w][jj+3];
    float w0 = wexp[w][h][jj], w1 = wexp[w][h][jj+1];
    float w2 = wexp[w][h][jj+2], w3 = wexp[w][h][jj+3];
    uint32_t v0 = xr[(size_t)s0 * 64 + lane];
    uint32_t v1 = xr[(size_t)s1 * 64 + lane];
    uint32_t v2 = xr[(size_t)s2 * 64 + lane];
    uint32_t v3 = xr[(size_t)s3 * 64 + lane];
    ax0 += w0 * __uint_as_float(v0 << 16) + w1 * __uint_as_float(v1 << 16);
    ay0 += w0 * __uint_as_float(v0 & 0xffff0000u) + w1 * __uint_as_float(v1 & 0xffff0000u);
    ax1 += w2 * __uint_as_float(v2 << 16) + w3 * __uint_as_float(v3 << 16);
    ay1 += w2 * __uint_as_float(v2 & 0xffff0000u) + w3 * __uint_as_float(v3 & 0xffff0000u);
  }
  for (; jj < dcap; ++jj) {
    int s0 = sidx[w][jj];
    float w0 = wexp[w][h][jj];
    uint32_t v0 = xr[(size_t)s0 * 64 + lane];
    ax0 += w0 * __uint_as_float(v0 << 16);
    ay0 += w0 * __uint_as_float(v0 & 0xffff0000u);
  }
  for (jj = CAP; jj < deg; ++jj) {
    int s = csr[start + jj];
    float v = a_src[(size_t)s * 8 + h] + adh;
    v = (v >= 0.f) ? v : 0.2f * v;
    float w0 = __expf(v - m);
    uint32_t v0 = xr[(size_t)s * 64 + lane];
    ax0 += w0 * __uint_as_float(v0 << 16);
    ay0 += w0 * __uint_as_float(v0 & 0xffff0000u);
  }
  float2 o = make_float2(fmaxf((ax0 + ax1) * invh, 0.f), fmaxf((ay0 + ay1) * invh, 0.f));
  *(float2*)&out[(size_t)dst * 128 + lane * 2] = o;
}

// ---------------- head MLP v2: out = W2·relu(W1·h + b1) + b2, W^T global, z in LDS ----------------
__global__ __launch_bounds__(256) void headmlp2_kernel(
    const float* __restrict__ h0, const float* __restrict__ h1,
    const float* __restrict__ W1t, const float* __restrict__ b1,
    const float* __restrict__ W2t, const float* __restrict__ b2,
    float* __restrict__ out, int N)
{
  constexpr int K = 128, M = 64, BN = 64;
  constexpr int COLG = 16, NODEG = 16, TM = 4, WP = 68;
  const int y = blockIdx.y;
  const float* in_ = y ? h1 : h0;
  const float* W1p = W1t + (size_t)y * 8192;   // [128][64]
  const float* b1p = b1 + y * 64;
  const float* W2p = W2t + (size_t)y * 4096;   // [64][64]
  const float* b2p = b2 + y * 64;
  float* outp = out + (size_t)y * N * 64;

  __shared__ float zl[BN * WP];
  const int tid = threadIdx.x;
  const int colq = tid % COLG;
  const int nodeg = tid / COLG;
  const int nb = blockIdx.x * BN;
  const float* xbase[TM];
  #pragma unroll
  for (int t = 0; t < TM; ++t) {
    int n = nb + nodeg * TM + t;
    xbase[t] = in_ + (size_t)(n < N ? n : N - 1) * K;
  }
  const float4 b1v = *(const float4*)&b1p[4 * colq];
  float acc[TM][4];
  #pragma unroll
  for (int t = 0; t < TM; ++t) {
    acc[t][0] = b1v.x; acc[t][1] = b1v.y; acc[t][2] = b1v.z; acc[t][3] = b1v.w;
  }
  #pragma unroll 2
  for (int k = 0; k < K; k += 4) {
    const float4 wv0 = *(const float4*)&W1p[(size_t)(k + 0) * M + 4 * colq];
    const float4 wv1 = *(const float4*)&W1p[(size_t)(k + 1) * M + 4 * colq];
    const float4 wv2 = *(const float4*)&W1p[(size_t)(k + 2) * M + 4 * colq];
    const float4 wv3 = *(const float4*)&W1p[(size_t)(k + 3) * M + 4 * colq];
    #pragma unroll
    for (int t = 0; t < TM; ++t) {
      const float4 xv = *(const float4*)(xbase[t] + k);
      acc[t][0] += xv.x * wv0.x + xv.y * wv1.x + xv.z * wv2.x + xv.w * wv3.x;
      acc[t][1] += xv.x * wv0.y + xv.y * wv1.y + xv.z * wv2.y + xv.w * wv3.y;
      acc[t][2] += xv.x * wv0.z + xv.y * wv1.z + xv.z * wv2.z + xv.w * wv3.z;
      acc[t][3] += xv.x * wv0.w + xv.y * wv1.w + xv.z * wv2.w + xv.w * wv3.w;
    }
  }
  #pragma unroll
  for (int t = 0; t < TM; ++t) {
    float4 z = make_float4(fmaxf(acc[t][0], 0.f), fmaxf(acc[t][1], 0.f),
                           fmaxf(acc[t][2], 0.f), fmaxf(acc[t][3], 0.f));
    *(float4*)&zl[(nodeg * TM + t) * WP + 4 * colq] = z;
  }
  __syncthreads();
  const float4 b2v = *(const float4*)&b2p[4 * colq];
  float acc2[TM][4];
  #pragma unroll
  for (int t = 0; t < TM; ++t) {
    acc2[t][0] = b2v.x; acc2[t][1] = b2v.y; acc2[t][2] = b2v.z; acc2[t][3] = b2v.w;
  }
  #pragma unroll 2
  for (int k2 = 0; k2 < 64; k2 += 4) {
    const float4 wv0 = *(const float4*)&W2p[(size_t)(k2 + 0) * M + 4 * colq];
    const float4 wv1 = *(const float4*)&W2p[(size_t)(k2 + 1) * M + 4 * colq];
    const float4 wv2 = *(const float4*)&W2p[(size_t)(k2 + 2) * M + 4 * colq];
    const float4 wv3 = *(const float4*)&W2p[(size_t)(k2 + 3) * M + 4 * colq];
    #pragma unroll
    for (int t = 0; t < TM; ++t) {
      const float4 xv = *(const float4*)&zl[(nodeg * TM + t) * WP + k2];
      acc2[t][0] += xv.x * wv0.x + xv.y * wv1.x + xv.z * wv2.x + xv.w * wv3.x;
      acc2[t][1] += xv.x * wv0.y + xv.y * wv1.y + xv.z * wv2.y + xv.w * wv3.y;
      acc2[t][2] += xv.x * wv0.z + xv.y * wv1.z + xv.z * wv2.z + xv.w * wv3.z;
      acc2[t][3] += xv.x * wv0.w + xv.y * wv1.w + xv.z * wv2.w + xv.w * wv3.w;
    }
  }
  #pragma unroll
  for (int t = 0; t < TM; ++t) {
    int n = nb + nodeg * TM + t;
    if (n < N) {
      *(float4*)&outp[(size_t)n * M + 4 * colq] =
          make_float4(acc2[t][0], acc2[t][1], acc2[t][2], acc2[t][3]);
    }
  }
}

// ---------------- launch ----------------
extern "C" void kernel_launch(void* const* d_in, const int* in_sizes, int n_in,
                              void* d_out, int out_size, void* d_ws, size_t ws_size,
                              hipStream_t stream) {
  (void)in_sizes; (void)n_in; (void)out_size; (void)ws_size;
  const float* x_stream  = (const float*)d_in[0];
  const float* x_device  = (const float*)d_in[1];
  const int*   edge_sd   = (const int*)d_in[2];
  const int*   edge_ds   = (const int*)d_in[3];
  const float* lstm_W_ih = (const float*)d_in[4];
  const float* lstm_b_ih = (const float*)d_in[5];
  const float* lstm_b_hh = (const float*)d_in[6];
  const float* sc_W      = (const float*)d_in[7];
  const float* sc_b      = (const float*)d_in[8];
  const float* dev_W     = (const float*)d_in[9];
  const float* dev_b     = (const float*)d_in[10];
  const float* proj_W    = (const float*)d_in[11];
  const float* proj_b    = (const float*)d_in[12];
  const float* att_src   = (const float*)d_in[13];
  const float* att_dst   = (const float*)d_in[14];
  // d_in[15..17] = q, k_W, k_b — mathematically unused (softmax over singleton stack)
  const float* outp_W1   = (const float*)d_in[18];
  const float* outp_b1   = (const float*)d_in[19];
  const float* outp_W2   = (const float*)d_in[20];
  const float* outp_b2   = (const float*)d_in[21];
  float* out_f = (float*)d_out;

  float* ws = (float*)d_ws;
  size_t off = 0;
  float* h0  = ws + off; off += (size_t)NS_N * 128;
  float* h1  = ws + off; off += (size_t)ND_N * 128;
  unsigned short* xb0 = (unsigned short*)(ws + off); off += (size_t)NS_N * 64;  // bf16 128/node
  unsigned short* xb1 = (unsigned short*)(ws + off); off += (size_t)ND_N * 64;
  float* as0 = ws + off; off += (size_t)NS_N * 8;
  float* ad0 = ws + off; off += (size_t)NS_N * 8;
  float* as1 = ws + off; off += (size_t)ND_N * 8;
  float* ad1 = ws + off; off += (size_t)ND_N * 8;
  float* wt  = ws + off; off += 100352;       // transposed weights
  int* ip = (int*)(ws + off);
  int* cnt    = ip; ip += ND_N + NS_N;       // [cnt_sd | cnt_ds]  (zeroed)
  int* totals = ip; ip += 2;                 // (zeroed, contiguous with cnt)
  int* rp     = ip; ip += ND_N + NS_N;
  int* cur    = ip; ip += ND_N + NS_N;
  int* csr_sd = ip; ip += E_N;
  int* csr_ds = ip; ip += E_N;

  hipMemsetAsync(cnt, 0, (size_t)(ND_N + NS_N + 2) * sizeof(int), stream);

  transpose_w_kernel<<<dim3(8, 10), 256, 0, stream>>>(
      proj_W, outp_W1, outp_W2, sc_W, dev_W, wt);

  const int EB = (E_N + 255) / 256;
  count2_kernel<<<EB, 256, 0, stream>>>(edge_sd + E_N, edge_ds + E_N, cnt, E_N);
  alloc_kernel<<<dim3((50000 + 255) / 256, 2), 256, 0, stream>>>(cnt, rp, cur, totals, 50000);
  fill2_kernel<<<dim3(EB, 2), 256, 0, stream>>>(edge_sd, edge_ds, cur, csr_sd, csr_ds, E_N);

  const int GB64 = (NS_N + 63) / 64;    // 782

  enc_fused2_kernel<<<dim3(GB64, 2), 256, 0, stream>>>(
      x_stream, lstm_W_ih, lstm_b_ih, lstm_b_hh, wt + 90112, sc_b, h0,
      x_device, wt + 96256, dev_b, h1, NS_N);

  for (int l = 0; l < 2; ++l) {
    dense7_kernel<128, 128, 64, false, true, true><<<dim3(GB64, 2), 256, 0, stream>>>(
        h0, wt + (size_t)(l * 2 + 0) * 16384, proj_b + (l * 2 + 0) * 128, xb0,
        att_src + (l * 2 + 0) * 128, att_dst + (l * 2 + 1) * 128, as0, ad0,
        h1, wt + (size_t)(l * 2 + 1) * 16384, proj_b + (l * 2 + 1) * 128, xb1,
        att_src + (l * 2 + 1) * 128, att_dst + (l * 2 + 0) * 128, as1, ad1, NS_N);
    att_agg5_kernel<<<dim3((ND_N + 3) / 4, 2), 256, 0, stream>>>(
        rp, cnt, csr_sd, as0, ad1, xb0, h1,
        rp + 50000, cnt + 50000, csr_ds, as1, ad0, xb1, h0, ND_N);
  }

  headmlp2_kernel<<<dim3(GB64, 2), 256, 0, stream>>>(
      h0, h1, wt + 65536, outp_b1, wt + 81920, outp_b2, out_f, NS_N);
}